// Round 12
// baseline (510.760 us; speedup 1.0000x reference)
//
#include <hip/hip_runtime.h>
#include <hip/hip_cooperative_groups.h>

namespace cg = cooperative_groups;

#define NRD   65536
#define DIMD  128
#define KCB   1024
#define RPB   64           // rows per tile
#define NTIL  (NRD / RPB)  // 1024 row-tiles
#define MARGIN 0.10f       // fp16 A&B: validated R7/R8/R9 (absmax 0)

typedef float f32x4 __attribute__((ext_vector_type(4)));
typedef _Float16 half8 __attribute__((ext_vector_type(8)));

// ---- workspace layout (bytes) ----
#define WS_ESQ   0          // 1024 f32
#define WS_CNT   4096       // 1 int
#define WS_LIST  8192       // 65536 int (ends 270336)
#define WS_B     270336     // 256 KB fp16 B blob (ends 532480)
#define WS_ET2   532480     // 512 KB embedT f32 (separate region; needs ws >= 1056768)
#define WS_NEED  1056768

__device__ inline half8 pack_h(float4 a, float4 b) {      // fp32 -> fp16 (v_cvt_f16_f32)
    half8 r;
    r[0]=(_Float16)a.x; r[1]=(_Float16)a.y; r[2]=(_Float16)a.z; r[3]=(_Float16)a.w;
    r[4]=(_Float16)b.x; r[5]=(_Float16)b.y; r[6]=(_Float16)b.z; r[7]=(_Float16)b.w;
    return r;
}

// ============================================================================
// MEGA: prep -> grid.sync -> vq (grid-stride tiles) -> grid.sync -> refine.
// One launch: kills 2 kernel gaps + 2 ramps/tails.  Phases have disjoint live
// ranges (R10 lesson: never inline refine into vq's live scope).
// ============================================================================
__global__ __launch_bounds__(512, 4) void mega(const float* __restrict__ x,
                                               const float* __restrict__ embed,
                                               float* __restrict__ esq,
                                               float4* __restrict__ bblob,
                                               f32x4* __restrict__ et4,
                                               float* __restrict__ out_q,
                                               float* __restrict__ out_idx,
                                               int* __restrict__ cnt,
                                               int* __restrict__ list) {
    __shared__ __align__(16) short Bb[32][512];         // 32 KB (A-stage + B-steps + ph3 xls alias)
    __shared__ float rbest[4][RPB];                     // 1 KB
    __shared__ int   rmeta[4][RPB];                     // 1 KB
    __shared__ float rb2[4][RPB];                       // 1 KB

    cg::grid_group grid = cg::this_grid();
    const int t    = threadIdx.x;
    const int lane = t & 63;
    const int w    = __builtin_amdgcn_readfirstlane(t >> 6);
    const int G    = gridDim.x;

    // ================= phase 1: prep (no LDS) =================
    // esq: one codebook row per wave
    for (int row = blockIdx.x * 8 + w; row < KCB; row += G * 8) {
        const float* rp = embed + (size_t)row * DIMD;
        float a = rp[lane], b = rp[lane + 64];
        float v = a * a + b * b;
        #pragma unroll
        for (int off = 32; off >= 1; off >>= 1) v += __shfl_xor(v, off, 64);
        if (lane == 0) esq[row] = v;
    }
    // bblob: unit u = s*2048 + ksh*1024 + ctg*64 + lane (R7/R8 proven layout)
    for (int u = blockIdx.x * 512 + t; u < 16384; u += G * 512) {
        int ln  = u & 63;
        int ctg = (u >> 6) & 15;
        int ksh = (u >> 10) & 1;
        int s   = u >> 11;
        int chunk = s >> 1, kh = s & 1;
        int ks = kh * 2 + ksh;
        int code = chunk * 256 + ctg * 16 + (ln & 15);
        int d0   = ks * 32 + (ln >> 4) * 8;
        const float4* e4 = (const float4*)(embed + (size_t)code * DIMD + d0);
        half8 v = pack_h(e4[0], e4[1]);
        bblob[u] = *(float4*)&v;
    }
    // et4 transpose, LDS-free: reads gather from L2-resident embed, writes coalesced
    {
        float* et4f = (float*)et4;
        for (int e = blockIdx.x * 512 + t; e < DIMD * KCB; e += G * 512) {
            int d = e >> 10, code = e & (KCB - 1);
            et4f[(size_t)d * KCB + code] = embed[(size_t)code * DIMD + d];
        }
    }
    if (blockIdx.x == 0 && t == 0) cnt[0] = 0;
    grid.sync();

    // ================= phase 2: vq, grid-stride over row-tiles =================
    {
        const int rg = w >> 2, cg2 = w & 3;
        const int l15 = lane & 15, l4 = lane >> 4;
        short (*Atrans)[4][512] = (short (*)[4][512])&Bb[0][0];   // 16 KB alias

        for (int tile = blockIdx.x; tile < NTIL; tile += G) {
            __syncthreads();                             // LDS safe to restage
            const int row0 = tile * RPB;

            const int ksA = w & 3, jh = w >> 2;
            const float4* xs = (const float4*)(x + (size_t)(row0 + lane) * DIMD + ksA * 32 + jh * 16);
            float4 xv0 = xs[0], xv1 = xs[1], xv2 = xs[2], xv3 = xs[3];

            const int rtA = lane >> 4, riA = lane & 15;
            *(half8*)&Atrans[ksA][rtA][((jh * 2 + 0) * 16 + riA) * 8] = pack_h(xv0, xv1);
            *(half8*)&Atrans[ksA][rtA][((jh * 2 + 1) * 16 + riA) * 8] = pack_h(xv2, xv3);
            asm volatile("s_waitcnt lgkmcnt(0)" ::: "memory");
            __builtin_amdgcn_s_barrier();                // Atrans published

            half8 ahr[4][2];
            #pragma unroll
            for (int ks = 0; ks < 4; ++ks)
                #pragma unroll
                for (int rt = 0; rt < 2; ++rt)
                    ahr[ks][rt] = *(const half8*)&Atrans[ks][rg * 2 + rt][lane * 8];
            asm volatile("s_waitcnt lgkmcnt(0)" ::: "memory");
            __builtin_amdgcn_s_barrier();                // Atrans dead; Bb free

#define GLDS(sv) do {                                                                                   \
    const char* g_ = (const char*)bblob + (size_t)(sv) * 32768 + ((size_t)w * 64 + lane) * 16;          \
    _Pragma("unroll")                                                                                   \
    for (int k_ = 0; k_ < 4; ++k_)                                                                      \
        __builtin_amdgcn_global_load_lds(                                                               \
            (const __attribute__((address_space(1))) unsigned int*)(g_ + k_ * 8192),                    \
            (__attribute__((address_space(3))) unsigned int*)&Bb[k_ * 8 + w][0], 16, 0, 0);             \
} while (0)

            GLDS(0);
            asm volatile("s_waitcnt vmcnt(0)" ::: "memory");
            __builtin_amdgcn_s_barrier();

            f32x4 acc[2][4];
            float best[2][4]; int bidx[2][4]; float b2[2][4];
            #pragma unroll
            for (int i = 0; i < 2; ++i)
                #pragma unroll
                for (int j = 0; j < 4; ++j) { best[i][j] = -1e30f; bidx[i][j] = 0; b2[i][j] = -1e30f; }

            const float* esqp = esq + cg2 * 64 + l15;
            float eq0 = 0.f, eq1 = 0.f, eq2 = 0.f, eq3 = 0.f;

#define STEP(khv) do {                                                                  \
    const int s_ = c * 2 + khv;                                                         \
    if (khv == 0) {                                                                     \
        eq0 = esqp[c * 256];      eq1 = esqp[c * 256 + 16];                             \
        eq2 = esqp[c * 256 + 32]; eq3 = esqp[c * 256 + 48];                             \
        _Pragma("unroll")                                                               \
        for (int i_ = 0; i_ < 2; ++i_)                                                  \
            _Pragma("unroll")                                                           \
            for (int j_ = 0; j_ < 4; ++j_) acc[i_][j_] = (f32x4){0.f, 0.f, 0.f, 0.f};   \
    }                                                                                   \
    half8 bh_[2][4];                                                                    \
    _Pragma("unroll")                                                                   \
    for (int ksh_ = 0; ksh_ < 2; ++ksh_)                                                \
        _Pragma("unroll")                                                               \
        for (int ct_ = 0; ct_ < 4; ++ct_)                                               \
            bh_[ksh_][ct_] = *(const half8*)&Bb[ksh_ * 16 + cg2 * 4 + ct_][lane * 8];   \
    asm volatile("s_waitcnt lgkmcnt(0)" ::: "memory");                                  \
    __builtin_amdgcn_s_barrier();           /* all waves' reads done */                 \
    if (s_ < 7) GLDS(s_ + 1);               /* overwrite in place */                    \
    _Pragma("unroll")                                                                   \
    for (int ksh_ = 0; ksh_ < 2; ++ksh_) {                                              \
        _Pragma("unroll")                                                               \
        for (int ct_ = 0; ct_ < 4; ++ct_) {                                             \
            _Pragma("unroll")                                                           \
            for (int rt_ = 0; rt_ < 2; ++rt_)                                           \
                acc[rt_][ct_] = __builtin_amdgcn_mfma_f32_16x16x32_f16(ahr[khv * 2 + ksh_][rt_], bh_[ksh_][ct_], acc[rt_][ct_], 0, 0, 0); \
        }                                                                               \
    }                                                                                   \
    if (khv == 1) {  /* chunk epilogue: second-best tracking */                         \
        _Pragma("unroll")                                                               \
        for (int ct_ = 0; ct_ < 4; ++ct_) {                                             \
            int code_ = c * 256 + cg2 * 64 + ct_ * 16 + l15;                            \
            float eq_ = (ct_ == 0) ? eq0 : (ct_ == 1) ? eq1 : (ct_ == 2) ? eq2 : eq3;   \
            _Pragma("unroll")                                                           \
            for (int rt_ = 0; rt_ < 2; ++rt_)                                           \
                _Pragma("unroll")                                                       \
                for (int r_ = 0; r_ < 4; ++r_) {                                        \
                    float sc_ = 2.0f * acc[rt_][ct_][r_] - eq_;                         \
                    b2[rt_][r_] = fmaxf(b2[rt_][r_], fminf(sc_, best[rt_][r_]));        \
                    if (sc_ > best[rt_][r_]) { best[rt_][r_] = sc_; bidx[rt_][r_] = code_; } \
                }                                                                       \
        }                                                                               \
    }                                                                                   \
    if (s_ < 7) {                                                                       \
        asm volatile("s_waitcnt vmcnt(0)" ::: "memory");   /* next step landed */       \
        __builtin_amdgcn_s_barrier();                                                   \
    }                                                                                   \
} while (0)

            for (int c = 0; c < 4; ++c) { STEP(0); STEP(1); }
#undef STEP
#undef GLDS

            // cross-lane reduce over the 16 code-lanes, ties -> smaller index
            #pragma unroll
            for (int rt = 0; rt < 2; ++rt)
                #pragma unroll
                for (int r = 0; r < 4; ++r) {
                    float v = best[rt][r]; int i = bidx[rt][r]; float s2 = b2[rt][r];
                    #pragma unroll
                    for (int off = 1; off < 16; off <<= 1) {
                        float ov = __shfl_xor(v, off, 64);
                        int   oi = __shfl_xor(i, off, 64);
                        float o2 = __shfl_xor(s2, off, 64);
                        s2 = fmaxf(fmaxf(s2, o2), fminf(v, ov));
                        bool sw = (ov > v) || (ov == v && oi < i);
                        if (sw) { v = ov; i = oi; }
                    }
                    if (l15 == 0) {
                        int rl = rg * 32 + rt * 16 + l4 * 4 + r;
                        rbest[cg2][rl] = v;
                        rmeta[cg2][rl] = i;
                        rb2[cg2][rl]   = s2;
                    }
                }
            __syncthreads();
            if (t < RPB) {  // merge the 4 codegroups per row
                float b = rbest[0][t]; int i = rmeta[0][t]; float s2 = rb2[0][t];
                #pragma unroll
                for (int g = 1; g < 4; ++g) {
                    float ob = rbest[g][t]; int oi = rmeta[g][t]; float o2 = rb2[g][t];
                    s2 = fmaxf(fmaxf(s2, o2), fminf(b, ob));
                    bool sw = (ob > b) || (ob == b && oi < i);
                    if (sw) { b = ob; i = oi; }
                }
                out_idx[row0 + t] = (float)i;
                if (s2 >= b - MARGIN) { int pos = atomicAdd(cnt, 1); list[pos] = row0 + t; }
                rmeta[0][t] = i;
            }
            __syncthreads();
            {   // cooperative gather of chosen codebook rows (8 threads x 64B per row)
                int row = t >> 3, part = t & 7;
                int idx = rmeta[0][row];
                const float4* src = (const float4*)(embed + (size_t)idx * DIMD + part * 16);
                float4* dst = (float4*)(out_q + (size_t)(row0 + row) * DIMD + part * 16);
                #pragma unroll
                for (int q = 0; q < 4; ++q) dst[q] = src[q];
            }
        }
    }
    grid.sync();

    // ================= phase 3: exact fp32 refine, one row per wave =================
    {
        const int n = cnt[0];
        float* xls = (float*)&Bb[0][0] + (size_t)w * 128;   // 512 B per wave, Bb is dead
        for (int j = blockIdx.x * 8 + w; j < n; j += G * 8) {
            const int row = list[j];
            float2 xv = *(const float2*)(x + (size_t)row * DIMD + lane * 2);
            xls[lane * 2]     = xv.x;
            xls[lane * 2 + 1] = xv.y;
            float s = xv.x * xv.x + xv.y * xv.y;
            #pragma unroll
            for (int off = 32; off >= 1; off >>= 1) s += __shfl_xor(s, off, 64);
            const float xsq = s;

            f32x4 racc[4];
            #pragma unroll
            for (int g = 0; g < 4; ++g) racc[g] = (f32x4){0.f, 0.f, 0.f, 0.f};

            asm volatile("s_waitcnt lgkmcnt(0)" ::: "memory");  // xls visible to own wave

            for (int d0 = 0; d0 < 32; ++d0) {
                float4 xd = *(const float4*)&xls[d0 * 4];
                #pragma unroll
                for (int dd = 0; dd < 4; ++dd) {
                    const f32x4* ep = et4 + (size_t)(d0 * 4 + dd) * 256 + lane;
                    f32x4 e0 = ep[0], e1 = ep[64], e2 = ep[128], e3 = ep[192];
                    float xsc = (dd == 0) ? xd.x : (dd == 1) ? xd.y
                              : (dd == 2) ? xd.z : xd.w;
                    racc[0] = e0 * xsc + racc[0];
                    racc[1] = e1 * xsc + racc[1];
                    racc[2] = e2 * xsc + racc[2];
                    racc[3] = e3 * xsc + racc[3];
                }
            }

            float bv = -1e30f; int bi = 0;
            #pragma unroll
            for (int g = 0; g < 4; ++g) {
                float4 eq = *(const float4*)&esq[g * 256 + lane * 4];
                #pragma unroll
                for (int c2 = 0; c2 < 4; ++c2) {
                    float eqv = (c2 == 0) ? eq.x : (c2 == 1) ? eq.y : (c2 == 2) ? eq.z : eq.w;
                    float sc = -(__fadd_rn(__fsub_rn(xsq, __fmul_rn(2.0f, racc[g][c2])), eqv));
                    int code = g * 256 + lane * 4 + c2;
                    if (sc > bv) { bv = sc; bi = code; }
                }
            }
            #pragma unroll
            for (int off = 32; off >= 1; off >>= 1) {
                float ov = __shfl_xor(bv, off, 64);
                int   oi = __shfl_xor(bi, off, 64);
                if (ov > bv || (ov == bv && oi < bi)) { bv = ov; bi = oi; }
            }
            if (lane == 0) out_idx[row] = (float)bi;
            if (lane < 32) {
                float4 v = ((const float4*)embed)[(size_t)bi * 32 + lane];
                ((float4*)out_q)[(size_t)row * 32 + lane] = v;
            }
        }
    }
}

// ============================================================================
// Fallback path (ws < WS_NEED): proven R7/R8 4-kernel pipeline, unchanged.
// ============================================================================
__global__ __launch_bounds__(256, 2) void prep_kernel(const float* __restrict__ embed,
                                                      float* __restrict__ esq,
                                                      float4* __restrict__ bblob,
                                                      float4* __restrict__ et4,
                                                      int* __restrict__ cnt,
                                                      int doTrans) {
    __shared__ float tile[64][129];
    const int t = threadIdx.x;
    {
        int gw   = blockIdx.x * 4 + (t >> 6);
        int lane = t & 63;
        const float* row = embed + (size_t)gw * DIMD;
        float a = row[lane], b = row[lane + 64];
        float v = a * a + b * b;
        #pragma unroll
        for (int off = 32; off >= 1; off >>= 1) v += __shfl_xor(v, off, 64);
        if (lane == 0) esq[gw] = v;
    }
    if (blockIdx.x < 64) {
        int tid  = blockIdx.x * 256 + t;
        int lane = tid & 63;
        int ctg  = (tid >> 6) & 15;
        int ksh  = (tid >> 10) & 1;
        int s    = tid >> 11;
        int chunk = s >> 1, kh = s & 1;
        int ks = kh * 2 + ksh;
        int code = chunk * 256 + ctg * 16 + (lane & 15);
        int d0   = ks * 32 + (lane >> 4) * 8;
        const float4* e4 = (const float4*)(embed + (size_t)code * DIMD + d0);
        half8 v = pack_h(e4[0], e4[1]);
        bblob[tid] = *(float4*)&v;
    }
    if (doTrans && blockIdx.x >= 64 && blockIdx.x < 80) {
        const int c0 = (blockIdx.x - 64) * 64;
        #pragma unroll
        for (int i = 0; i < 8; ++i) {
            int u = t + i * 256;
            int row = u >> 5, col4 = u & 31;
            float4 v = ((const float4*)embed)[(size_t)(c0 + row) * 32 + col4];
            tile[row][col4 * 4 + 0] = v.x;
            tile[row][col4 * 4 + 1] = v.y;
            tile[row][col4 * 4 + 2] = v.z;
            tile[row][col4 * 4 + 3] = v.w;
        }
        __syncthreads();
        #pragma unroll
        for (int i = 0; i < 8; ++i) {
            int u = t + i * 256;
            int d = u >> 4, off = u & 15;
            float4 v;
            v.x = tile[off * 4 + 0][d];
            v.y = tile[off * 4 + 1][d];
            v.z = tile[off * 4 + 2][d];
            v.w = tile[off * 4 + 3][d];
            et4[(size_t)d * 256 + (c0 >> 2) + off] = v;
        }
    }
    if (blockIdx.x == 128 && t == 0) cnt[0] = 0;
}

__global__ __launch_bounds__(512, 4) void vq_mfma(const float* __restrict__ x,
                                                  const float* __restrict__ embed,
                                                  const float* __restrict__ esq,
                                                  const float4* __restrict__ bblob,
                                                  float* __restrict__ out_q,
                                                  float* __restrict__ out_idx,
                                                  int* __restrict__ cnt,
                                                  int* __restrict__ list) {
    __shared__ __align__(16) short Bb[32][512];
    __shared__ float rbest[4][RPB];
    __shared__ int   rmeta[4][RPB];
    __shared__ float rb2[4][RPB];

    const int t    = threadIdx.x;
    const int lane = t & 63;
    const int w    = __builtin_amdgcn_readfirstlane(t >> 6);
    const int rg   = w >> 2, cg2 = w & 3;
    const int l15  = lane & 15, l4 = lane >> 4;
    const int row0 = blockIdx.x * RPB;

    short (*Atrans)[4][512] = (short (*)[4][512])&Bb[0][0];

    const int ksA = w & 3, jh = w >> 2;
    const float4* xs = (const float4*)(x + (size_t)(row0 + lane) * DIMD + ksA * 32 + jh * 16);
    float4 xv0 = xs[0], xv1 = xs[1], xv2 = xs[2], xv3 = xs[3];

    const int rtA = lane >> 4, riA = lane & 15;
    *(half8*)&Atrans[ksA][rtA][((jh * 2 + 0) * 16 + riA) * 8] = pack_h(xv0, xv1);
    *(half8*)&Atrans[ksA][rtA][((jh * 2 + 1) * 16 + riA) * 8] = pack_h(xv2, xv3);
    asm volatile("s_waitcnt lgkmcnt(0)" ::: "memory");
    __builtin_amdgcn_s_barrier();

    half8 ahr[4][2];
    #pragma unroll
    for (int ks = 0; ks < 4; ++ks)
        #pragma unroll
        for (int rt = 0; rt < 2; ++rt)
            ahr[ks][rt] = *(const half8*)&Atrans[ks][rg * 2 + rt][lane * 8];
    asm volatile("s_waitcnt lgkmcnt(0)" ::: "memory");
    __builtin_amdgcn_s_barrier();

#define GLDS(sv) do {                                                                                   \
    const char* g_ = (const char*)bblob + (size_t)(sv) * 32768 + ((size_t)w * 64 + lane) * 16;          \
    _Pragma("unroll")                                                                                   \
    for (int k_ = 0; k_ < 4; ++k_)                                                                      \
        __builtin_amdgcn_global_load_lds(                                                               \
            (const __attribute__((address_space(1))) unsigned int*)(g_ + k_ * 8192),                    \
            (__attribute__((address_space(3))) unsigned int*)&Bb[k_ * 8 + w][0], 16, 0, 0);             \
} while (0)

    GLDS(0);
    asm volatile("s_waitcnt vmcnt(0)" ::: "memory");
    __builtin_amdgcn_s_barrier();

    f32x4 acc[2][4];
    float best[2][4]; int bidx[2][4]; float b2[2][4];
    #pragma unroll
    for (int i = 0; i < 2; ++i)
        #pragma unroll
        for (int j = 0; j < 4; ++j) { best[i][j] = -1e30f; bidx[i][j] = 0; b2[i][j] = -1e30f; }

    const float* esqp = esq + cg2 * 64 + l15;
    float eq0 = 0.f, eq1 = 0.f, eq2 = 0.f, eq3 = 0.f;

#define STEP(khv) do {                                                                  \
    const int s_ = c * 2 + khv;                                                         \
    if (khv == 0) {                                                                     \
        eq0 = esqp[c * 256];      eq1 = esqp[c * 256 + 16];                             \
        eq2 = esqp[c * 256 + 32]; eq3 = esqp[c * 256 + 48];                             \
        _Pragma("unroll")                                                               \
        for (int i_ = 0; i_ < 2; ++i_)                                                  \
            _Pragma("unroll")                                                           \
            for (int j_ = 0; j_ < 4; ++j_) acc[i_][j_] = (f32x4){0.f, 0.f, 0.f, 0.f};   \
    }                                                                                   \
    half8 bh_[2][4];                                                                    \
    _Pragma("unroll")                                                                   \
    for (int ksh_ = 0; ksh_ < 2; ++ksh_)                                                \
        _Pragma("unroll")                                                               \
        for (int ct_ = 0; ct_ < 4; ++ct_)                                               \
            bh_[ksh_][ct_] = *(const half8*)&Bb[ksh_ * 16 + cg2 * 4 + ct_][lane * 8];   \
    asm volatile("s_waitcnt lgkmcnt(0)" ::: "memory");                                  \
    __builtin_amdgcn_s_barrier();                                                       \
    if (s_ < 7) GLDS(s_ + 1);                                                           \
    _Pragma("unroll")                                                                   \
    for (int ksh_ = 0; ksh_ < 2; ++ksh_) {                                              \
        _Pragma("unroll")                                                               \
        for (int ct_ = 0; ct_ < 4; ++ct_) {                                             \
            _Pragma("unroll")                                                           \
            for (int rt_ = 0; rt_ < 2; ++rt_)                                           \
                acc[rt_][ct_] = __builtin_amdgcn_mfma_f32_16x16x32_f16(ahr[khv * 2 + ksh_][rt_], bh_[ksh_][ct_], acc[rt_][ct_], 0, 0, 0); \
        }                                                                               \
    }                                                                                   \
    if (khv == 1) {                                                                     \
        _Pragma("unroll")                                                               \
        for (int ct_ = 0; ct_ < 4; ++ct_) {                                             \
            int code_ = c * 256 + cg2 * 64 + ct_ * 16 + l15;                            \
            float eq_ = (ct_ == 0) ? eq0 : (ct_ == 1) ? eq1 : (ct_ == 2) ? eq2 : eq3;   \
            _Pragma("unroll")                                                           \
            for (int rt_ = 0; rt_ < 2; ++rt_)                                           \
                _Pragma("unroll")                                                       \
                for (int r_ = 0; r_ < 4; ++r_) {                                        \
                    float sc_ = 2.0f * acc[rt_][ct_][r_] - eq_;                         \
                    b2[rt_][r_] = fmaxf(b2[rt_][r_], fminf(sc_, best[rt_][r_]));        \
                    if (sc_ > best[rt_][r_]) { best[rt_][r_] = sc_; bidx[rt_][r_] = code_; } \
                }                                                                       \
        }                                                                               \
    }                                                                                   \
    if (s_ < 7) {                                                                       \
        asm volatile("s_waitcnt vmcnt(0)" ::: "memory");                                \
        __builtin_amdgcn_s_barrier();                                                   \
    }                                                                                   \
} while (0)

    for (int c = 0; c < 4; ++c) { STEP(0); STEP(1); }
#undef STEP
#undef GLDS

    #pragma unroll
    for (int rt = 0; rt < 2; ++rt)
        #pragma unroll
        for (int r = 0; r < 4; ++r) {
            float v = best[rt][r]; int i = bidx[rt][r]; float s2 = b2[rt][r];
            #pragma unroll
            for (int off = 1; off < 16; off <<= 1) {
                float ov = __shfl_xor(v, off, 64);
                int   oi = __shfl_xor(i, off, 64);
                float o2 = __shfl_xor(s2, off, 64);
                s2 = fmaxf(fmaxf(s2, o2), fminf(v, ov));
                bool sw = (ov > v) || (ov == v && oi < i);
                if (sw) { v = ov; i = oi; }
            }
            if (l15 == 0) {
                int rl = rg * 32 + rt * 16 + l4 * 4 + r;
                rbest[cg2][rl] = v;
                rmeta[cg2][rl] = i;
                rb2[cg2][rl]   = s2;
            }
        }
    __syncthreads();
    if (t < RPB) {
        float b = rbest[0][t]; int i = rmeta[0][t]; float s2 = rb2[0][t];
        #pragma unroll
        for (int g = 1; g < 4; ++g) {
            float ob = rbest[g][t]; int oi = rmeta[g][t]; float o2 = rb2[g][t];
            s2 = fmaxf(fmaxf(s2, o2), fminf(b, ob));
            bool sw = (ob > b) || (ob == b && oi < i);
            if (sw) { b = ob; i = oi; }
        }
        out_idx[row0 + t] = (float)i;
        if (s2 >= b - MARGIN) { int pos = atomicAdd(cnt, 1); list[pos] = row0 + t; }
        rmeta[0][t] = i;
    }
    __syncthreads();
    {
        int row = t >> 3, part = t & 7;
        int idx = rmeta[0][row];
        const float4* src = (const float4*)(embed + (size_t)idx * DIMD + part * 16);
        float4* dst = (float4*)(out_q + (size_t)(row0 + row) * DIMD + part * 16);
        #pragma unroll
        for (int q = 0; q < 4; ++q) dst[q] = src[q];
    }
}

__global__ __launch_bounds__(256, 2) void trans_kernel(const float* __restrict__ embed,
                                                       float4* __restrict__ et4) {
    __shared__ float tile[64][129];
    const int t = threadIdx.x;
    const int c0 = blockIdx.x * 64;
    #pragma unroll
    for (int i = 0; i < 8; ++i) {
        int u = t + i * 256;
        int row = u >> 5, col4 = u & 31;
        float4 v = ((const float4*)embed)[(size_t)(c0 + row) * 32 + col4];
        tile[row][col4 * 4 + 0] = v.x;
        tile[row][col4 * 4 + 1] = v.y;
        tile[row][col4 * 4 + 2] = v.z;
        tile[row][col4 * 4 + 3] = v.w;
    }
    __syncthreads();
    #pragma unroll
    for (int i = 0; i < 8; ++i) {
        int u = t + i * 256;
        int d = u >> 4, off = u & 15;
        float4 v;
        v.x = tile[off * 4 + 0][d];
        v.y = tile[off * 4 + 1][d];
        v.z = tile[off * 4 + 2][d];
        v.w = tile[off * 4 + 3][d];
        et4[(size_t)d * 256 + (c0 >> 2) + off] = v;
    }
}

__global__ __launch_bounds__(256, 2) void refine_kernel(const float* __restrict__ x,
                                                        const float* __restrict__ embed,
                                                        const float* __restrict__ esq,
                                                        const f32x4* __restrict__ et4,
                                                        float* __restrict__ out_q,
                                                        float* __restrict__ out_idx,
                                                        const int* __restrict__ cnt,
                                                        const int* __restrict__ list) {
    __shared__ float xls[4][4][128];
    const int t = threadIdx.x, lane = t & 63, w = t >> 6;
    const int n = cnt[0];
    const int njobs = (n + 3) >> 2;
    for (int job = blockIdx.x * 4 + w; job < njobs; job += gridDim.x * 4) {
        int rows[4];
        #pragma unroll
        for (int i = 0; i < 4; ++i) {
            int li = job * 4 + i; if (li >= n) li = n - 1;
            rows[i] = list[li];
        }
        float xsq[4];
        #pragma unroll
        for (int i = 0; i < 4; ++i) {
            float2 xv = *(const float2*)(x + (size_t)rows[i] * DIMD + lane * 2);
            xls[w][i][lane * 2]     = xv.x;
            xls[w][i][lane * 2 + 1] = xv.y;
            float s = xv.x * xv.x + xv.y * xv.y;
            #pragma unroll
            for (int off = 32; off >= 1; off >>= 1) s += __shfl_xor(s, off, 64);
            xsq[i] = s;
        }
        f32x4 acc[4][4];
        #pragma unroll
        for (int i = 0; i < 4; ++i)
            #pragma unroll
            for (int g = 0; g < 4; ++g) acc[i][g] = (f32x4){0.f, 0.f, 0.f, 0.f};

        for (int d0 = 0; d0 < 32; ++d0) {
            float4 xd[4];
            #pragma unroll
            for (int i = 0; i < 4; ++i) xd[i] = *(const float4*)&xls[w][i][d0 * 4];
            #pragma unroll
            for (int dd = 0; dd < 4; ++dd) {
                const f32x4* ep = et4 + (size_t)(d0 * 4 + dd) * 256 + lane;
                f32x4 e0 = ep[0], e1 = ep[64], e2 = ep[128], e3 = ep[192];
                #pragma unroll
                for (int i = 0; i < 4; ++i) {
                    float xsc = (dd == 0) ? xd[i].x : (dd == 1) ? xd[i].y
                              : (dd == 2) ? xd[i].z : xd[i].w;
                    acc[i][0] = e0 * xsc + acc[i][0];
                    acc[i][1] = e1 * xsc + acc[i][1];
                    acc[i][2] = e2 * xsc + acc[i][2];
                    acc[i][3] = e3 * xsc + acc[i][3];
                }
            }
        }

        #pragma unroll
        for (int i = 0; i < 4; ++i) {
            float bv = -1e30f; int bi = 0;
            #pragma unroll
            for (int g = 0; g < 4; ++g) {
                float4 eq = *(const float4*)&esq[g * 256 + lane * 4];
                #pragma unroll
                for (int c2 = 0; c2 < 4; ++c2) {
                    float eqv = (c2 == 0) ? eq.x : (c2 == 1) ? eq.y : (c2 == 2) ? eq.z : eq.w;
                    float sc = -(__fadd_rn(__fsub_rn(xsq[i], __fmul_rn(2.0f, acc[i][g][c2])), eqv));
                    int code = g * 256 + lane * 4 + c2;
                    if (sc > bv) { bv = sc; bi = code; }
                }
            }
            #pragma unroll
            for (int off = 32; off >= 1; off >>= 1) {
                float ov = __shfl_xor(bv, off, 64);
                int   oi = __shfl_xor(bi, off, 64);
                if (ov > bv || (ov == bv && oi < bi)) { bv = ov; bi = oi; }
            }
            if (lane == 0) out_idx[rows[i]] = (float)bi;
            if (lane < 32) {
                float4 v = ((const float4*)embed)[(size_t)bi * 32 + lane];
                ((float4*)out_q)[(size_t)rows[i] * 32 + lane] = v;
            }
        }
    }
}

extern "C" void kernel_launch(void* const* d_in, const int* in_sizes, int n_in,
                              void* d_out, int out_size, void* d_ws, size_t ws_size,
                              hipStream_t stream) {
    const float* x     = (const float*)d_in[0];
    const float* embed = (const float*)d_in[1];
    float* out     = (float*)d_out;
    float* out_q   = out;
    float* out_idx = out + (size_t)NRD * DIMD;

    char*  wsb  = (char*)d_ws;
    float* esq  = (float*)(wsb + WS_ESQ);
    int*   cnt  = (int*)(wsb + WS_CNT);
    int*   list = (int*)(wsb + WS_LIST);
    float4* bblob = (float4*)(wsb + WS_B);

    const int fused = (ws_size >= (size_t)WS_NEED) ? 1 : 0;
    f32x4* et4 = fused ? (f32x4*)(wsb + WS_ET2) : (f32x4*)(wsb + WS_B);

    if (fused) {
        static int maxb = -1;
        if (maxb < 0) {
            hipOccupancyMaxActiveBlocksPerMultiprocessor(&maxb, mega, 512, 0);
            if (maxb < 1) maxb = 1;
        }
        int G = maxb * 256; if (G > NTIL) G = NTIL;
        void* args[] = {(void*)&x, (void*)&embed, (void*)&esq, (void*)&bblob,
                        (void*)&et4, (void*)&out_q, (void*)&out_idx,
                        (void*)&cnt, (void*)&list};
        hipLaunchCooperativeKernel((void*)mega, dim3(G), dim3(512), args, 0, stream);
    } else {
        prep_kernel  <<<dim3(256),  dim3(256), 0, stream>>>(embed, esq, bblob, (float4*)et4, cnt, 0);
        vq_mfma      <<<dim3(NTIL), dim3(512), 0, stream>>>(x, embed, esq, bblob, out_q, out_idx, cnt, list);
        trans_kernel <<<dim3(16),   dim3(256), 0, stream>>>(embed, (float4*)et4);
        refine_kernel<<<dim3(256),  dim3(256), 0, stream>>>(x, embed, esq, et4, out_q, out_idx, cnt, list);
    }
}

// Round 13
// 78.692 us; speedup vs baseline: 6.4906x; 6.4906x over previous
//
#include <hip/hip_runtime.h>

#define NRD   65536
#define DIMD  128
#define KCB   1024
#define RPB   32           // rows per block (4-wave blocks)
#define NBLK  (NRD / RPB)  // 2048
#define MARGIN 0.10f       // fp16 A&B: validated R7/R8 (absmax 0)

typedef float f32x4 __attribute__((ext_vector_type(4)));
typedef _Float16 half8 __attribute__((ext_vector_type(8)));

// ---- workspace layout (bytes) ----
#define WS_ESQ   0          // 1024 f32
#define WS_CNT   4096       // 1 int
#define WS_LIST  8192       // 65536 int (ends 270336)
#define WS_B     270336     // 256 KB fp16 B blob (ends 532480)
#define WS_ET2   532480     // 512 KB embedT f32 (separate region; needs ws >= 1056768)
#define WS_NEED  1056768

__device__ inline half8 pack_h(float4 a, float4 b) {      // fp32 -> fp16 (v_cvt_f16_f32)
    half8 r;
    r[0]=(_Float16)a.x; r[1]=(_Float16)a.y; r[2]=(_Float16)a.z; r[3]=(_Float16)a.w;
    r[4]=(_Float16)b.x; r[5]=(_Float16)b.y; r[6]=(_Float16)b.z; r[7]=(_Float16)b.w;
    return r;
}

// ---- fused prep: esq + fp16 B-blob split + (optional) transpose + cnt reset ----
// blob unit u = s*2048 + ksh*1024 + ctg*64 + lane ; s = chunk*2 + kh (8 steps of 32 KB)
// code = chunk*256 + ctg*16 + (lane&15) ; d0 = (kh*2+ksh)*32 + (lane>>4)*8
__global__ __launch_bounds__(256, 2) void prep_kernel(const float* __restrict__ embed,
                                                      float* __restrict__ esq,
                                                      float4* __restrict__ bblob,
                                                      float4* __restrict__ et4,
                                                      int* __restrict__ cnt,
                                                      int doTrans) {
    __shared__ float tile[64][129];
    const int t = threadIdx.x;
    {
        int gw   = blockIdx.x * 4 + (t >> 6);
        int lane = t & 63;
        const float* row = embed + (size_t)gw * DIMD;
        float a = row[lane], b = row[lane + 64];
        float v = a * a + b * b;
        #pragma unroll
        for (int off = 32; off >= 1; off >>= 1) v += __shfl_xor(v, off, 64);
        if (lane == 0) esq[gw] = v;
    }
    if (blockIdx.x < 64) {
        int tid  = blockIdx.x * 256 + t;             // 0..16383
        int lane = tid & 63;
        int ctg  = (tid >> 6) & 15;
        int ksh  = (tid >> 10) & 1;
        int s    = tid >> 11;                        // 0..7
        int chunk = s >> 1, kh = s & 1;
        int ks = kh * 2 + ksh;
        int l15 = lane & 15, l4 = lane >> 4;
        int code = chunk * 256 + ctg * 16 + l15;
        int d0   = ks * 32 + l4 * 8;
        const float4* e4 = (const float4*)(embed + (size_t)code * DIMD + d0);
        half8 v = pack_h(e4[0], e4[1]);
        bblob[tid] = *(float4*)&v;
    }
    if (doTrans && blockIdx.x >= 64 && blockIdx.x < 80) {
        const int c0 = (blockIdx.x - 64) * 64;
        #pragma unroll
        for (int i = 0; i < 8; ++i) {
            int u = t + i * 256;
            int row = u >> 5, col4 = u & 31;
            float4 v = ((const float4*)embed)[(size_t)(c0 + row) * 32 + col4];
            tile[row][col4 * 4 + 0] = v.x;
            tile[row][col4 * 4 + 1] = v.y;
            tile[row][col4 * 4 + 2] = v.z;
            tile[row][col4 * 4 + 3] = v.w;
        }
        __syncthreads();
        #pragma unroll
        for (int i = 0; i < 8; ++i) {
            int u = t + i * 256;
            int d = u >> 4, off = u & 15;
            float4 v;
            v.x = tile[off * 4 + 0][d];
            v.y = tile[off * 4 + 1][d];
            v.z = tile[off * 4 + 2][d];
            v.w = tile[off * 4 + 3][d];
            et4[(size_t)d * 256 + (c0 >> 2) + off] = v;
        }
    }
    if (blockIdx.x == 128 && t == 0) cnt[0] = 0;
}

// ---- main MFMA kernel: R7 proven STEP schedule, 4-wave blocks (RPB=32, 2048 blocks). ----
__global__ __launch_bounds__(256, 4) void vq_mfma(const float* __restrict__ x,
                                                  const float* __restrict__ embed,
                                                  const float* __restrict__ esq,
                                                  const float4* __restrict__ bblob,
                                                  float* __restrict__ out_q,
                                                  float* __restrict__ out_idx,
                                                  int* __restrict__ cnt,
                                                  int* __restrict__ list) {
    __shared__ __align__(16) short Bb[32][512];         // 32 KB: single fat step buffer
    __shared__ float rbest[4][RPB];                     // 512 B
    __shared__ int   rmeta[4][RPB];                     // 512 B
    __shared__ float rb2[4][RPB];                       // 512 B

    const int t    = threadIdx.x;
    const int lane = t & 63;
    const int w    = __builtin_amdgcn_readfirstlane(t >> 6);   // 0..3: cg AND K-slice for A
    const int l15  = lane & 15, l4 = lane >> 4;
    const int row0 = blockIdx.x * RPB;

    // A staging aliased over the first 8 KB of Bb (dead once ahr is in registers)
    short (*Atrans)[2][512] = (short (*)[2][512])&Bb[0][0];    // [ks][rt][lane*8]

    // x tile: 32 rows x 128 d.  Per wave: K-slice w (32 dims); lane&31 = row, lane>>5 = d-half.
    const int rA  = lane & 31;          // row within tile
    const int jh  = lane >> 5;          // 16-dim half within the 32-dim K-slice
    const float4* xs = (const float4*)(x + (size_t)(row0 + rA) * DIMD + w * 32 + jh * 16);
    float4 xv0 = xs[0], xv1 = xs[1], xv2 = xs[2], xv3 = xs[3];

    const int rtA = (lane >> 4) & 1, riA = lane & 15;
    *(half8*)&Atrans[w][rtA][((jh * 2 + 0) * 16 + riA) * 8] = pack_h(xv0, xv1);
    *(half8*)&Atrans[w][rtA][((jh * 2 + 1) * 16 + riA) * 8] = pack_h(xv2, xv3);
    asm volatile("s_waitcnt lgkmcnt(0)" ::: "memory");
    __builtin_amdgcn_s_barrier();                        // Atrans published

    half8 ahr[4][2];
    #pragma unroll
    for (int ks = 0; ks < 4; ++ks)
        #pragma unroll
        for (int rt = 0; rt < 2; ++rt)
            ahr[ks][rt] = *(const half8*)&Atrans[ks][rt][lane * 8];
    asm volatile("s_waitcnt lgkmcnt(0)" ::: "memory");
    __builtin_amdgcn_s_barrier();                        // all waves done with Atrans; Bb free

    // step sv (32 KB): 8 issues/thread (256 threads); LDS linear = global - s*32768
#define GLDS(sv) do {                                                                                   \
    const char* g_ = (const char*)bblob + (size_t)(sv) * 32768 + ((size_t)w * 64 + lane) * 16;          \
    _Pragma("unroll")                                                                                   \
    for (int k_ = 0; k_ < 8; ++k_)                                                                      \
        __builtin_amdgcn_global_load_lds(                                                               \
            (const __attribute__((address_space(1))) unsigned int*)(g_ + k_ * 4096),                    \
            (__attribute__((address_space(3))) unsigned int*)&Bb[k_ * 4 + w][0], 16, 0, 0);             \
} while (0)

    GLDS(0);
    asm volatile("s_waitcnt vmcnt(0)" ::: "memory");     // step-0 B landed
    __builtin_amdgcn_s_barrier();

    f32x4 acc[2][4];
    float best[2][4]; int bidx[2][4]; float b2[2][4];
    #pragma unroll
    for (int i = 0; i < 2; ++i)
        #pragma unroll
        for (int j = 0; j < 4; ++j) { best[i][j] = -1e30f; bidx[i][j] = 0; b2[i][j] = -1e30f; }

    const float* esqp = esq + w * 64 + l15;
    float eq0 = 0.f, eq1 = 0.f, eq2 = 0.f, eq3 = 0.f;

    // step = (chunk c, d-half khv): buffer holds step's 32 KB (drained at prev barrier).
    // reads -> lgkm0+barrier -> GLDS(s+1) in place -> 16 MFMA -> [epilogue] -> vmcnt0+barrier
#define STEP(khv) do {                                                                  \
    const int s_ = c * 2 + khv;                                                         \
    if (khv == 0) {                                                                     \
        eq0 = esqp[c * 256];      eq1 = esqp[c * 256 + 16];                             \
        eq2 = esqp[c * 256 + 32]; eq3 = esqp[c * 256 + 48];                             \
        _Pragma("unroll")                                                               \
        for (int i_ = 0; i_ < 2; ++i_)                                                  \
            _Pragma("unroll")                                                           \
            for (int j_ = 0; j_ < 4; ++j_) acc[i_][j_] = (f32x4){0.f, 0.f, 0.f, 0.f};   \
    }                                                                                   \
    half8 bh_[2][4];                                                                    \
    _Pragma("unroll")                                                                   \
    for (int ksh_ = 0; ksh_ < 2; ++ksh_)                                                \
        _Pragma("unroll")                                                               \
        for (int ct_ = 0; ct_ < 4; ++ct_)                                               \
            bh_[ksh_][ct_] = *(const half8*)&Bb[ksh_ * 16 + w * 4 + ct_][lane * 8];     \
    asm volatile("s_waitcnt lgkmcnt(0)" ::: "memory");                                  \
    __builtin_amdgcn_s_barrier();           /* all waves' reads done */                 \
    if (s_ < 7) GLDS(s_ + 1);               /* overwrite in place */                    \
    _Pragma("unroll")                                                                   \
    for (int ksh_ = 0; ksh_ < 2; ++ksh_) {                                              \
        _Pragma("unroll")                                                               \
        for (int ct_ = 0; ct_ < 4; ++ct_) {                                             \
            _Pragma("unroll")                                                           \
            for (int rt_ = 0; rt_ < 2; ++rt_)                                           \
                acc[rt_][ct_] = __builtin_amdgcn_mfma_f32_16x16x32_f16(ahr[khv * 2 + ksh_][rt_], bh_[ksh_][ct_], acc[rt_][ct_], 0, 0, 0); \
        }                                                                               \
    }                                                                                   \
    if (khv == 1) {  /* chunk epilogue: second-best tracking */                         \
        _Pragma("unroll")                                                               \
        for (int ct_ = 0; ct_ < 4; ++ct_) {                                             \
            int code_ = c * 256 + w * 64 + ct_ * 16 + l15;                              \
            float eq_ = (ct_ == 0) ? eq0 : (ct_ == 1) ? eq1 : (ct_ == 2) ? eq2 : eq3;   \
            _Pragma("unroll")                                                           \
            for (int rt_ = 0; rt_ < 2; ++rt_)                                           \
                _Pragma("unroll")                                                       \
                for (int r_ = 0; r_ < 4; ++r_) {                                        \
                    float sc_ = 2.0f * acc[rt_][ct_][r_] - eq_;                         \
                    b2[rt_][r_] = fmaxf(b2[rt_][r_], fminf(sc_, best[rt_][r_]));        \
                    if (sc_ > best[rt_][r_]) { best[rt_][r_] = sc_; bidx[rt_][r_] = code_; } \
                }                                                                       \
        }                                                                               \
    }                                                                                   \
    if (s_ < 7) {                                                                       \
        asm volatile("s_waitcnt vmcnt(0)" ::: "memory");   /* next step landed */       \
        __builtin_amdgcn_s_barrier();                                                   \
    }                                                                                   \
} while (0)

    for (int c = 0; c < 4; ++c) {       // 4 chunks of 256 codes, 2 fat steps each
        STEP(0); STEP(1);
    }
#undef STEP
#undef GLDS

    // ---- cross-lane reduce over the 16 code-lanes, ties -> smaller index ----
    #pragma unroll
    for (int rt = 0; rt < 2; ++rt)
        #pragma unroll
        for (int r = 0; r < 4; ++r) {
            float v = best[rt][r]; int i = bidx[rt][r]; float s2 = b2[rt][r];
            #pragma unroll
            for (int off = 1; off < 16; off <<= 1) {
                float ov = __shfl_xor(v, off, 64);
                int   oi = __shfl_xor(i, off, 64);
                float o2 = __shfl_xor(s2, off, 64);
                s2 = fmaxf(fmaxf(s2, o2), fminf(v, ov));
                bool sw = (ov > v) || (ov == v && oi < i);
                if (sw) { v = ov; i = oi; }
            }
            if (l15 == 0) {
                int rl = rt * 16 + l4 * 4 + r;           // 0..31
                rbest[w][rl] = v;
                rmeta[w][rl] = i;
                rb2[w][rl]   = s2;
            }
        }
    __syncthreads();
    if (t < RPB) {  // merge the 4 codegroups per row
        float b = rbest[0][t]; int i = rmeta[0][t]; float s2 = rb2[0][t];
        #pragma unroll
        for (int g = 1; g < 4; ++g) {
            float ob = rbest[g][t]; int oi = rmeta[g][t]; float o2 = rb2[g][t];
            s2 = fmaxf(fmaxf(s2, o2), fminf(b, ob));
            bool sw = (ob > b) || (ob == b && oi < i);
            if (sw) { b = ob; i = oi; }
        }
        out_idx[row0 + t] = (float)i;
        if (s2 >= b - MARGIN) { int pos = atomicAdd(cnt, 1); list[pos] = row0 + t; }
        rmeta[0][t] = i;
    }
    __syncthreads();
    {   // cooperative gather of chosen codebook rows (8 threads x 64B per row)
        int row = t >> 3, part = t & 7;                  // 32 rows x 8 parts = 256 threads
        int idx = rmeta[0][row];
        const float4* src = (const float4*)(embed + (size_t)idx * DIMD + part * 16);
        float4* dst = (float4*)(out_q + (size_t)(row0 + row) * DIMD + part * 16);
        #pragma unroll
        for (int q = 0; q < 4; ++q) dst[q] = src[q];
    }
}

// ---- standalone transpose (fallback when ws too small to fuse) ----
__global__ __launch_bounds__(256, 2) void trans_kernel(const float* __restrict__ embed,
                                                       float4* __restrict__ et4) {
    __shared__ float tile[64][129];
    const int t = threadIdx.x;
    const int c0 = blockIdx.x * 64;
    #pragma unroll
    for (int i = 0; i < 8; ++i) {
        int u = t + i * 256;
        int row = u >> 5, col4 = u & 31;
        float4 v = ((const float4*)embed)[(size_t)(c0 + row) * 32 + col4];
        tile[row][col4 * 4 + 0] = v.x;
        tile[row][col4 * 4 + 1] = v.y;
        tile[row][col4 * 4 + 2] = v.z;
        tile[row][col4 * 4 + 3] = v.w;
    }
    __syncthreads();
    #pragma unroll
    for (int i = 0; i < 8; ++i) {
        int u = t + i * 256;
        int d = u >> 4, off = u & 15;
        float4 v;
        v.x = tile[off * 4 + 0][d];
        v.y = tile[off * 4 + 1][d];
        v.z = tile[off * 4 + 2][d];
        v.w = tile[off * 4 + 3][d];
        et4[(size_t)d * 256 + (c0 >> 2) + off] = v;
    }
}

// ---- exact fp32 refine, coalesced via embedT (unchanged, proven) ----
__global__ __launch_bounds__(256, 2) void refine_kernel(const float* __restrict__ x,
                                                        const float* __restrict__ embed,
                                                        const float* __restrict__ esq,
                                                        const f32x4* __restrict__ et4,
                                                        float* __restrict__ out_q,
                                                        float* __restrict__ out_idx,
                                                        const int* __restrict__ cnt,
                                                        const int* __restrict__ list) {
    __shared__ float xls[4][4][128];
    const int t = threadIdx.x, lane = t & 63, w = t >> 6;
    const int n = cnt[0];
    const int njobs = (n + 3) >> 2;
    for (int job = blockIdx.x * 4 + w; job < njobs; job += gridDim.x * 4) {
        int rows[4];
        #pragma unroll
        for (int i = 0; i < 4; ++i) {
            int li = job * 4 + i; if (li >= n) li = n - 1;
            rows[i] = list[li];
        }
        float xsq[4];
        #pragma unroll
        for (int i = 0; i < 4; ++i) {
            float2 xv = *(const float2*)(x + (size_t)rows[i] * DIMD + lane * 2);
            xls[w][i][lane * 2]     = xv.x;
            xls[w][i][lane * 2 + 1] = xv.y;
            float s = xv.x * xv.x + xv.y * xv.y;
            #pragma unroll
            for (int off = 32; off >= 1; off >>= 1) s += __shfl_xor(s, off, 64);
            xsq[i] = s;
        }
        f32x4 acc[4][4];
        #pragma unroll
        for (int i = 0; i < 4; ++i)
            #pragma unroll
            for (int g = 0; g < 4; ++g) acc[i][g] = (f32x4){0.f, 0.f, 0.f, 0.f};

        for (int d0 = 0; d0 < 32; ++d0) {
            float4 xd[4];
            #pragma unroll
            for (int i = 0; i < 4; ++i) xd[i] = *(const float4*)&xls[w][i][d0 * 4];
            #pragma unroll
            for (int dd = 0; dd < 4; ++dd) {
                const f32x4* ep = et4 + (size_t)(d0 * 4 + dd) * 256 + lane;
                f32x4 e0 = ep[0], e1 = ep[64], e2 = ep[128], e3 = ep[192];
                #pragma unroll
                for (int i = 0; i < 4; ++i) {
                    float xsc = (dd == 0) ? xd[i].x : (dd == 1) ? xd[i].y
                              : (dd == 2) ? xd[i].z : xd[i].w;
                    acc[i][0] = e0 * xsc + acc[i][0];
                    acc[i][1] = e1 * xsc + acc[i][1];
                    acc[i][2] = e2 * xsc + acc[i][2];
                    acc[i][3] = e3 * xsc + acc[i][3];
                }
            }
        }

        #pragma unroll
        for (int i = 0; i < 4; ++i) {
            float bv = -1e30f; int bi = 0;
            #pragma unroll
            for (int g = 0; g < 4; ++g) {
                float4 eq = *(const float4*)&esq[g * 256 + lane * 4];
                #pragma unroll
                for (int c2 = 0; c2 < 4; ++c2) {
                    float eqv = (c2 == 0) ? eq.x : (c2 == 1) ? eq.y : (c2 == 2) ? eq.z : eq.w;
                    float sc = -(__fadd_rn(__fsub_rn(xsq[i], __fmul_rn(2.0f, acc[i][g][c2])), eqv));
                    int code = g * 256 + lane * 4 + c2;
                    if (sc > bv) { bv = sc; bi = code; }
                }
            }
            #pragma unroll
            for (int off = 32; off >= 1; off >>= 1) {
                float ov = __shfl_xor(bv, off, 64);
                int   oi = __shfl_xor(bi, off, 64);
                if (ov > bv || (ov == bv && oi < bi)) { bv = ov; bi = oi; }
            }
            if (lane == 0) out_idx[rows[i]] = (float)bi;
            if (lane < 32) {
                float4 v = ((const float4*)embed)[(size_t)bi * 32 + lane];
                ((float4*)out_q)[(size_t)rows[i] * 32 + lane] = v;
            }
        }
    }
}

extern "C" void kernel_launch(void* const* d_in, const int* in_sizes, int n_in,
                              void* d_out, int out_size, void* d_ws, size_t ws_size,
                              hipStream_t stream) {
    const float* x     = (const float*)d_in[0];
    const float* embed = (const float*)d_in[1];
    float* out     = (float*)d_out;
    float* out_q   = out;
    float* out_idx = out + (size_t)NRD * DIMD;

    char*  wsb  = (char*)d_ws;
    float* esq  = (float*)(wsb + WS_ESQ);
    int*   cnt  = (int*)(wsb + WS_CNT);
    int*   list = (int*)(wsb + WS_LIST);
    float4* bblob = (float4*)(wsb + WS_B);

    const int fused = (ws_size >= (size_t)WS_NEED) ? 1 : 0;
    f32x4* et4 = fused ? (f32x4*)(wsb + WS_ET2) : (f32x4*)(wsb + WS_B);

    prep_kernel  <<<dim3(256),  dim3(256), 0, stream>>>(embed, esq, bblob, (float4*)et4, cnt, fused);
    vq_mfma      <<<dim3(NBLK), dim3(256), 0, stream>>>(x, embed, esq, bblob, out_q, out_idx, cnt, list);
    if (!fused)
        trans_kernel<<<dim3(16), dim3(256), 0, stream>>>(embed, (float4*)et4);
    refine_kernel<<<dim3(256),  dim3(256), 0, stream>>>(x, embed, esq, et4, out_q, out_idx, cnt, list);
}